// Round 1
// baseline (908.379 us; speedup 1.0000x reference)
//
#include <hip/hip_runtime.h>

// Integrate-and-fire SNN input layer.
//   per t: m += image[t]; spk = m >= 1.0f; m -= (spk ? 1.0f : 0.0f)
// Outputs (concatenated in d_out, float32): spikes [T, N] (0.0/1.0), mempot [N].
// Pure streaming, HBM-bound: ~1.06 GB total traffic -> roofline ~170 us @6.3 TB/s.

constexpr int TSTEPS = 32;
constexpr int N_NEU  = 4194304;

__global__ __launch_bounds__(256) void snn_if_kernel(
    const float* __restrict__ image,      // [T, N]
    const float* __restrict__ mempot_in,  // [N]
    float* __restrict__ spikes,           // [T, N] out
    float* __restrict__ mempot_out)       // [N] out
{
    const int i = (blockIdx.x * 256 + threadIdx.x) * 4;  // 4 neurons / thread

    float4 m = *reinterpret_cast<const float4*>(mempot_in + i);

#pragma unroll
    for (int t = 0; t < TSTEPS; ++t) {
        const size_t off = (size_t)t * N_NEU + i;
        float4 img = *reinterpret_cast<const float4*>(image + off);
        float4 s;
        m.x += img.x; s.x = (m.x >= 1.0f) ? 1.0f : 0.0f; m.x -= s.x;
        m.y += img.y; s.y = (m.y >= 1.0f) ? 1.0f : 0.0f; m.y -= s.y;
        m.z += img.z; s.z = (m.z >= 1.0f) ? 1.0f : 0.0f; m.z -= s.z;
        m.w += img.w; s.w = (m.w >= 1.0f) ? 1.0f : 0.0f; m.w -= s.w;
        *reinterpret_cast<float4*>(spikes + off) = s;
    }

    *reinterpret_cast<float4*>(mempot_out + i) = m;
}

extern "C" void kernel_launch(void* const* d_in, const int* in_sizes, int n_in,
                              void* d_out, int out_size, void* d_ws, size_t ws_size,
                              hipStream_t stream) {
    const float* image     = (const float*)d_in[0];   // [32, 4194304]
    const float* mempot_in = (const float*)d_in[1];   // [4194304]
    float* out = (float*)d_out;
    float* spikes     = out;                          // first T*N elements
    float* mempot_out = out + (size_t)TSTEPS * N_NEU; // last N elements

    const int threads = 256;
    const int blocks  = N_NEU / (4 * threads);        // 4096 blocks
    snn_if_kernel<<<blocks, threads, 0, stream>>>(image, mempot_in, spikes, mempot_out);
}

// Round 3
// 900.762 us; speedup vs baseline: 1.0085x; 1.0085x over previous
//
#include <hip/hip_runtime.h>

// Integrate-and-fire SNN input layer.
//   per t: m += image[t]; spk = (m >= 1.0f); m -= spk
// Outputs (concatenated in d_out, float32): spikes [T, N] (0/1), mempot [N].
// Pure streaming: ~1.06 GB total HBM traffic -> roofline ~173 us @ 6.3 TB/s.
//
// R3 notes: nontemporal builtins need native vector types, not
// HIP_vector_type -> use ext_vector_type(4). Unroll capped at 4;
// __launch_bounds__(256,8) pins 32 waves/CU (VGPR<=64).

constexpr int TSTEPS = 32;
constexpr int N_NEU  = 4194304;

typedef float vf4 __attribute__((ext_vector_type(4)));

__global__ __launch_bounds__(256, 8) void snn_if_kernel(
    const float* __restrict__ image,      // [T, N]
    const float* __restrict__ mempot_in,  // [N]
    float* __restrict__ spikes,           // [T, N] out
    float* __restrict__ mempot_out)       // [N] out
{
    const int i = (blockIdx.x * 256 + threadIdx.x) * 4;  // 4 neurons / thread

    vf4 m = __builtin_nontemporal_load(
        reinterpret_cast<const vf4*>(mempot_in + i));

#pragma unroll 4
    for (int t = 0; t < TSTEPS; ++t) {
        const size_t off = (size_t)t * N_NEU + i;
        vf4 img = __builtin_nontemporal_load(
            reinterpret_cast<const vf4*>(image + off));
        vf4 s;
        m.x += img.x; s.x = (m.x >= 1.0f) ? 1.0f : 0.0f; m.x -= s.x;
        m.y += img.y; s.y = (m.y >= 1.0f) ? 1.0f : 0.0f; m.y -= s.y;
        m.z += img.z; s.z = (m.z >= 1.0f) ? 1.0f : 0.0f; m.z -= s.z;
        m.w += img.w; s.w = (m.w >= 1.0f) ? 1.0f : 0.0f; m.w -= s.w;
        __builtin_nontemporal_store(s, reinterpret_cast<vf4*>(spikes + off));
    }

    __builtin_nontemporal_store(m, reinterpret_cast<vf4*>(mempot_out + i));
}

extern "C" void kernel_launch(void* const* d_in, const int* in_sizes, int n_in,
                              void* d_out, int out_size, void* d_ws, size_t ws_size,
                              hipStream_t stream) {
    const float* image     = (const float*)d_in[0];   // [32, 4194304]
    const float* mempot_in = (const float*)d_in[1];   // [4194304]
    float* out = (float*)d_out;
    float* spikes     = out;                          // first T*N elements
    float* mempot_out = out + (size_t)TSTEPS * N_NEU; // last N elements

    const int threads = 256;
    const int blocks  = N_NEU / (4 * threads);        // 4096 blocks
    snn_if_kernel<<<blocks, threads, 0, stream>>>(image, mempot_in, spikes, mempot_out);
}